// Round 2
// baseline (1322.044 us; speedup 1.0000x reference)
//
#include <hip/hip_runtime.h>
#include <math.h>

constexpr int   NGc    = 128;
constexpr int   NCELL  = NGc * NGc;
constexpr int   NBIN   = 128 * 32;          // bin = (bx, by>>2) : 4096
constexpr float DTc    = 1e-4f;
constexpr float DXc    = 1.0f / 128.0f;
constexpr float INV_DX = 128.0f;
constexpr float P_VOLc = (DXc * 0.5f) * (DXc * 0.5f);
constexpr float P_MASSc = P_VOLc * 1.0f;
constexpr float GRAV   = 9.8f;
constexpr float STRESS_COEF = -DTc * P_VOLc * 4.0f * INV_DX * INV_DX;

// ---------------------------------------------------------------------------
// S1: bin to 4096 bins (cell-row x col-group). LDS hist + local rank ->
// key = bin<<20 | pos_in_bin.
// ---------------------------------------------------------------------------
constexpr int S1_PPT = 16;
constexpr int S1_BLK = 1024;

__global__ __launch_bounds__(1024) void bin_kernel(
    const float2* __restrict__ x, unsigned* __restrict__ key,
    unsigned* __restrict__ gcnt, int n)
{
    __shared__ unsigned hist[NBIN];
#pragma unroll
    for (int j = 0; j < NBIN / S1_BLK; j++)
        hist[threadIdx.x + j * S1_BLK] = 0;
    __syncthreads();

    int base_i = blockIdx.x * (S1_BLK * S1_PPT);
    unsigned t_arr[S1_PPT], r_arr[S1_PPT];
#pragma unroll
    for (int k = 0; k < S1_PPT; k++) {
        int i = base_i + k * S1_BLK + threadIdx.x;
        unsigned t = 0, r = 0;
        if (i < n) {
            float2 xi = x[i];
            int bx = (int)floorf(xi.x * INV_DX - 0.5f);
            int by = (int)floorf(xi.y * INV_DX - 0.5f);
            t = (unsigned)(bx * 32 + (by >> 2));
            r = atomicAdd(&hist[t], 1u);
        }
        t_arr[k] = t; r_arr[k] = r;
    }
    __syncthreads();

#pragma unroll
    for (int j = 0; j < NBIN / S1_BLK; j++) {
        int b = threadIdx.x + j * S1_BLK;
        unsigned c = hist[b];
        __syncthreads();
        hist[b] = c ? atomicAdd(&gcnt[b], c) : 0u;
        __syncthreads();
    }

#pragma unroll
    for (int k = 0; k < S1_PPT; k++) {
        int i = base_i + k * S1_BLK + threadIdx.x;
        if (i < n)
            key[i] = (t_arr[k] << 20) | (hist[t_arr[k]] + r_arr[k]);
    }
}

// ---------------------------------------------------------------------------
// S2: exclusive scan over 4096 bin counts (single block, 4/thread) + sentinel
// ---------------------------------------------------------------------------
__global__ __launch_bounds__(1024) void scan_kernel(
    const unsigned* __restrict__ gcnt, unsigned* __restrict__ binoff)
{
    __shared__ unsigned s[1024];
    int t = threadIdx.x;
    unsigned v0 = gcnt[4 * t], v1 = gcnt[4 * t + 1];
    unsigned v2 = gcnt[4 * t + 2], v3 = gcnt[4 * t + 3];
    unsigned p = v0 + v1 + v2 + v3;
    s[t] = p;
    __syncthreads();
    for (int d = 1; d < 1024; d <<= 1) {
        unsigned add = (t >= d) ? s[t - d] : 0u;
        __syncthreads();
        s[t] += add;
        __syncthreads();
    }
    unsigned base = s[t] - p;
    binoff[4 * t]     = base;
    binoff[4 * t + 1] = base + v0;
    binoff[4 * t + 2] = base + v0 + v1;
    binoff[4 * t + 3] = base + v0 + v1 + v2;
    if (t == 1023) binoff[4096] = s[1023];
}

// ---------------------------------------------------------------------------
// Stage A: NN stress, LDS-staged weights (proven codegen), 2 particles per
// thread so every wave-uniform ds_read_b128 weight-row broadcast is amortized
// over 2 dot products (stagea is DS-throughput-bound: 256 ds_read_b128 *
// ~12cyc * 61 waves/CU ~= 78us == observed 80us). Explicit 4-way partial
// sums break the 16-deep fmac dependency chains. Writes out_F directly.
// Scatter packed 32B record {x,y,a00,a01,a10,a11,pvx,pvy} to bin-sorted slot.
// ---------------------------------------------------------------------------
constexpr int A_PPT = 2;

__global__ __launch_bounds__(256) void stagea_kernel(
    const float2* __restrict__ x, const float2* __restrict__ v,
    const float4* __restrict__ C, const float4* __restrict__ F,
    const float* __restrict__ W1, const float* __restrict__ b1,
    const float* __restrict__ W2, const float* __restrict__ b2,
    const float* __restrict__ W3, const float* __restrict__ b3,
    const float* __restrict__ W4,
    const unsigned* __restrict__ key, const unsigned* __restrict__ binoff,
    float4* __restrict__ recs, float4* __restrict__ out_F, int n)
{
    __shared__ float sW1[32];
    __shared__ float sW2[256], sW2T[256];
    __shared__ float sW3[256], sW3T[256];
    __shared__ float sb1[16], sb2[16], sb3[16], sW4[16];

    {
        int t = threadIdx.x;
        float w2 = W2[t], w3 = W3[t];
        sW2[t] = w2;  sW2T[(t & 15) * 16 + (t >> 4)] = w2;
        sW3[t] = w3;  sW3T[(t & 15) * 16 + (t >> 4)] = w3;
        if (t < 32) sW1[t] = W1[t];
        if (t < 16) { sb1[t] = b1[t]; sb2[t] = b2[t]; sb3[t] = b3[t]; sW4[t] = W4[t]; }
    }
    __syncthreads();

    const float4* W2r  = (const float4*)sW2;    // row j = W2r[4j .. 4j+3]
    const float4* W2Tr = (const float4*)sW2T;
    const float4* W3r  = (const float4*)sW3;
    const float4* W3Tr = (const float4*)sW3T;

    int base = blockIdx.x * (256 * A_PPT) + threadIdx.x;

    bool  ok[A_PPT];
    float2 xi[A_PPT];
    float4 Ci[A_PPT];
    float Fn00[A_PPT], Fn01[A_PPT], Fn10[A_PPT], Fn11[A_PPT];
    float Cm00[A_PPT], Cm01[A_PPT], Cm11[A_PPT];
    float tr[A_PPT], delta[A_PPT], gate[A_PPT];
    float feat0[A_PPT], feat1[A_PPT];
    float h1[A_PPT][16], h2[A_PPT][16], dh3[A_PPT][16], dh2[A_PPT][16];

#pragma unroll
    for (int p = 0; p < A_PPT; p++) {
        int i = base + p * 256;
        ok[p] = (i < n);
        int ii = ok[p] ? i : 0;

        xi[p] = x[ii];
        Ci[p] = C[ii];
        float4 Fi = F[ii];

        Fn00[p] = Fi.x + DTc * (Ci[p].x * Fi.x + Ci[p].y * Fi.z);
        Fn01[p] = Fi.y + DTc * (Ci[p].x * Fi.y + Ci[p].y * Fi.w);
        Fn10[p] = Fi.z + DTc * (Ci[p].z * Fi.x + Ci[p].w * Fi.z);
        Fn11[p] = Fi.w + DTc * (Ci[p].z * Fi.y + Ci[p].w * Fi.w);

        if (ok[p]) out_F[i] = make_float4(Fn00[p], Fn01[p], Fn10[p], Fn11[p]);

        Cm00[p] = Fn00[p] * Fn00[p] + Fn10[p] * Fn10[p];
        Cm01[p] = Fn00[p] * Fn01[p] + Fn10[p] * Fn11[p];
        Cm11[p] = Fn01[p] * Fn01[p] + Fn11[p] * Fn11[p];

        tr[p]  = Cm00[p] + Cm11[p];
        float det = Cm00[p] * Cm11[p] - Cm01[p] * Cm01[p];
        float g   = tr[p] * tr[p] - 4.0f * det;
        gate[p]  = (g > 1e-8f) ? 1.0f : 0.0f;
        delta[p] = sqrtf(fmaxf(g, 1e-8f));
        feat0[p] = 0.5f * (tr[p] + delta[p]);
        feat1[p] = 0.5f * (tr[p] - delta[p]);
    }

    // layer 1 (weights read once per j, shared across particles)
#pragma unroll
    for (int j = 0; j < 16; j++) {
        float wa = sW1[2 * j], wb = sW1[2 * j + 1], bb = sb1[j];
#pragma unroll
        for (int p = 0; p < A_PPT; p++)
            h1[p][j] = fmaxf(wa * feat0[p] + wb * feat1[p] + bb, 0.0f);
    }

    // layer 2
#pragma unroll
    for (int j = 0; j < 16; j++) {
        float4 w0 = W2r[4 * j], w1 = W2r[4 * j + 1], w2 = W2r[4 * j + 2], w3 = W2r[4 * j + 3];
        float bb = sb2[j];
#pragma unroll
        for (int p = 0; p < A_PPT; p++) {
            float a0 = w0.x * h1[p][0]  + w0.y * h1[p][1]  + w0.z * h1[p][2]  + w0.w * h1[p][3];
            float a1 = w1.x * h1[p][4]  + w1.y * h1[p][5]  + w1.z * h1[p][6]  + w1.w * h1[p][7];
            float a2 = w2.x * h1[p][8]  + w2.y * h1[p][9]  + w2.z * h1[p][10] + w2.w * h1[p][11];
            float a3 = w3.x * h1[p][12] + w3.y * h1[p][13] + w3.z * h1[p][14] + w3.w * h1[p][15];
            h2[p][j] = fmaxf(bb + ((a0 + a1) + (a2 + a3)), 0.0f);
        }
    }

    // layer 3 forward fused with dh3 (h3 itself never stored)
#pragma unroll
    for (int j = 0; j < 16; j++) {
        float4 w0 = W3r[4 * j], w1 = W3r[4 * j + 1], w2 = W3r[4 * j + 2], w3 = W3r[4 * j + 3];
        float bb = sb3[j], w4j = sW4[j];
#pragma unroll
        for (int p = 0; p < A_PPT; p++) {
            float a0 = w0.x * h2[p][0]  + w0.y * h2[p][1]  + w0.z * h2[p][2]  + w0.w * h2[p][3];
            float a1 = w1.x * h2[p][4]  + w1.y * h2[p][5]  + w1.z * h2[p][6]  + w1.w * h2[p][7];
            float a2 = w2.x * h2[p][8]  + w2.y * h2[p][9]  + w2.z * h2[p][10] + w2.w * h2[p][11];
            float a3 = w3.x * h2[p][12] + w3.y * h2[p][13] + w3.z * h2[p][14] + w3.w * h2[p][15];
            float a = bb + ((a0 + a1) + (a2 + a3));
            dh3[p][j] = (a > 0.0f) ? w4j : 0.0f;
        }
    }

    // backward through W3^T
#pragma unroll
    for (int kk = 0; kk < 16; kk++) {
        float4 w0 = W3Tr[4 * kk], w1 = W3Tr[4 * kk + 1], w2 = W3Tr[4 * kk + 2], w3 = W3Tr[4 * kk + 3];
#pragma unroll
        for (int p = 0; p < A_PPT; p++) {
            float a0 = w0.x * dh3[p][0]  + w0.y * dh3[p][1]  + w0.z * dh3[p][2]  + w0.w * dh3[p][3];
            float a1 = w1.x * dh3[p][4]  + w1.y * dh3[p][5]  + w1.z * dh3[p][6]  + w1.w * dh3[p][7];
            float a2 = w2.x * dh3[p][8]  + w2.y * dh3[p][9]  + w2.z * dh3[p][10] + w2.w * dh3[p][11];
            float a3 = w3.x * dh3[p][12] + w3.y * dh3[p][13] + w3.z * dh3[p][14] + w3.w * dh3[p][15];
            float a  = (a0 + a1) + (a2 + a3);
            dh2[p][kk] = (h2[p][kk] > 0.0f) ? a : 0.0f;
        }
    }

    // backward through W2^T and W1^T
    float dfeat0[A_PPT], dfeat1[A_PPT];
#pragma unroll
    for (int p = 0; p < A_PPT; p++) { dfeat0[p] = 0.0f; dfeat1[p] = 0.0f; }

#pragma unroll
    for (int kk = 0; kk < 16; kk++) {
        float4 w0 = W2Tr[4 * kk], w1 = W2Tr[4 * kk + 1], w2 = W2Tr[4 * kk + 2], w3 = W2Tr[4 * kk + 3];
        float wa = sW1[2 * kk], wb = sW1[2 * kk + 1];
#pragma unroll
        for (int p = 0; p < A_PPT; p++) {
            float a0 = w0.x * dh2[p][0]  + w0.y * dh2[p][1]  + w0.z * dh2[p][2]  + w0.w * dh2[p][3];
            float a1 = w1.x * dh2[p][4]  + w1.y * dh2[p][5]  + w1.z * dh2[p][6]  + w1.w * dh2[p][7];
            float a2 = w2.x * dh2[p][8]  + w2.y * dh2[p][9]  + w2.z * dh2[p][10] + w2.w * dh2[p][11];
            float a3 = w3.x * dh2[p][12] + w3.y * dh2[p][13] + w3.z * dh2[p][14] + w3.w * dh2[p][15];
            float a  = (a0 + a1) + (a2 + a3);
            float dh1k = (h1[p][kk] > 0.0f) ? a : 0.0f;
            dfeat0[p] += wa * dh1k;
            dfeat1[p] += wb * dh1k;
        }
    }

    // epilogue per particle
#pragma unroll
    for (int p = 0; p < A_PPT; p++) {
        if (!ok[p]) continue;
        int i = base + p * 256;

        float half_sum  = 0.5f * (dfeat0[p] + dfeat1[p]);
        float half_diff = 0.5f * (dfeat0[p] - dfeat1[p]);
        float inv_delta = 1.0f / delta[p];
        float dtr  = half_sum + half_diff * tr[p] * inv_delta * gate[p];
        float ddet = half_diff * (-2.0f) * inv_delta * gate[p];

        float S00 = 2.0f * (dtr + ddet * Cm11[p]);
        float S11 = 2.0f * (dtr + ddet * Cm00[p]);
        float S01 = -2.0f * ddet * Cm01[p];

        float dF00 = Fn00[p] * S00 + Fn01[p] * S01;
        float dF01 = Fn00[p] * S01 + Fn01[p] * S11;
        float dF10 = Fn10[p] * S00 + Fn11[p] * S01;
        float dF11 = Fn10[p] * S01 + Fn11[p] * S11;

        float a00 = STRESS_COEF * dF00 + P_MASSc * Ci[p].x;
        float a01 = STRESS_COEF * dF01 + P_MASSc * Ci[p].y;
        float a10 = STRESS_COEF * dF10 + P_MASSc * Ci[p].z;
        float a11 = STRESS_COEF * dF11 + P_MASSc * Ci[p].w;

        float2 vi = v[i];
        unsigned k = key[i];
        unsigned pos = binoff[k >> 20] + (k & 0xFFFFFu);

        recs[2 * (size_t)pos]     = make_float4(xi[p].x, xi[p].y, a00, a01);
        recs[2 * (size_t)pos + 1] = make_float4(a10, a11, P_MASSc * vi.x, P_MASSc * vi.y);
    }
}

// ---------------------------------------------------------------------------
// Gather-form grid build: one wave per grid node, register accumulate,
// butterfly reduce, fused grid update. No atomics.
// ---------------------------------------------------------------------------
__global__ __launch_bounds__(256) void grid_gather_kernel(
    const float4* __restrict__ recs, const unsigned* __restrict__ binoff,
    float2* __restrict__ gv)
{
    int wid  = threadIdx.x >> 6;
    int lane = threadIdx.x & 63;
    int node = blockIdx.x * 4 + wid;
    int gi = node >> 7;
    int gj = node & 127;

    const float gxx = (float)gi * DXc;
    const float gxy = (float)gj * DXc;

    float accx = 0.0f, accy = 0.0f, accm = 0.0f;

    int c0 = max(gj - 2, 0) >> 2;
    int c1 = min(gj, 127) >> 2;

#pragma unroll
    for (int r = 0; r < 3; r++) {
        int bx = gi - 2 + r;
        if (bx < 0 || bx > 127) continue;
        int lo = (int)binoff[bx * 32 + c0];
        int hi = (int)binoff[bx * 32 + c1 + 1];
        for (int k = lo + lane; k < hi; k += 64) {
            float4 r0 = recs[2 * (size_t)k];
            float4 r1 = recs[2 * (size_t)k + 1];

            float py = r0.y * INV_DX;
            int   by = (int)floorf(py - 0.5f);
            int   jj = gj - by;
            bool  ok = (jj >= 0) && (jj <= 2);

            float fy = py - (float)by;
            float fx = r0.x * INV_DX - (float)bx;

            float wx;
            if (r == 0)      wx = 0.5f * (fx - 0.5f) * (fx - 0.5f);   // ii = 2
            else if (r == 1) wx = 0.75f - (fx - 1.0f) * (fx - 1.0f);  // ii = 1
            else             wx = 0.5f * (1.5f - fx) * (1.5f - fx);   // ii = 0

            float wy0 = 0.5f * (1.5f - fy) * (1.5f - fy);
            float wy1 = 0.75f - (fy - 1.0f) * (fy - 1.0f);
            float wy2 = 0.5f * (fy - 0.5f) * (fy - 0.5f);
            float wy = (jj == 0) ? wy0 : ((jj == 1) ? wy1 : wy2);

            float wt = ok ? (wx * wy) : 0.0f;
            float dxp = gxx - r0.x;
            float dyp = gxy - r0.y;
            accx += wt * (r1.z + r0.z * dxp + r0.w * dyp);
            accy += wt * (r1.w + r1.x * dxp + r1.y * dyp);
            accm += wt * P_MASSc;
        }
    }

#pragma unroll
    for (int off = 32; off >= 1; off >>= 1) {
        accx += __shfl_xor(accx, off, 64);
        accy += __shfl_xor(accy, off, 64);
        accm += __shfl_xor(accm, off, 64);
    }

    if (lane == 0) {
        float vx = accx, vy = accy;
        if (accm > 0.0f) {
            float inv_m = 1.0f / accm;
            vx *= inv_m;
            vy *= inv_m;
        }
        vy -= DTc * GRAV;
        if (gi < 3)        vx = fmaxf(vx, 0.0f);
        if (gi >= NGc - 3) vx = fminf(vx, 0.0f);
        if (gj < 3)        vy = fmaxf(vy, 0.0f);
        if (gj >= NGc - 3) vy = fminf(vy, 0.0f);
        gv[node] = make_float2(vx, vy);
    }
}

// ---------------------------------------------------------------------------
// G2P (Fnew already written by stagea; no C/F reads here)
// ---------------------------------------------------------------------------
__global__ __launch_bounds__(256) void g2p_kernel(
    const float2* __restrict__ x, const float2* __restrict__ v,
    const int* __restrict__ material, const float* __restrict__ Jp,
    const float2* __restrict__ gv,
    float2* __restrict__ out_x, float2* __restrict__ out_v,
    float4* __restrict__ out_C,
    float* __restrict__ out_mat, float* __restrict__ out_Jp, int n)
{
    int i = blockIdx.x * 256 + threadIdx.x;
    if (i >= n) return;

    float2 xi = x[i];
    float2 vi = v[i];

    float px = xi.x * INV_DX, py = xi.y * INV_DX;
    int   bx = (int)floorf(px - 0.5f);
    int   by = (int)floorf(py - 0.5f);
    float fx = px - (float)bx;
    float fy = py - (float)by;
    float wxs[3] = {0.5f * (1.5f - fx) * (1.5f - fx),
                    0.75f - (fx - 1.0f) * (fx - 1.0f),
                    0.5f * (fx - 0.5f) * (fx - 0.5f)};
    float wys[3] = {0.5f * (1.5f - fy) * (1.5f - fy),
                    0.75f - (fy - 1.0f) * (fy - 1.0f),
                    0.5f * (fy - 0.5f) * (fy - 0.5f)};

    float accvx = 0.0f, accvy = 0.0f;
    float accC00 = 0.0f, accC01 = 0.0f, accC10 = 0.0f, accC11 = 0.0f;

#pragma unroll
    for (int ii = 0; ii < 3; ii++) {
        float gxx = (float)(bx + ii) * DXc;
#pragma unroll
        for (int jj = 0; jj < 3; jj++) {
            float wt = wxs[ii] * wys[jj];
            float2 gvn = gv[(bx + ii) * NGc + (by + jj)];
            float gxy = (float)(by + jj) * DXc;
            accvx  += wt * gvn.x;
            accvy  += wt * gvn.y;
            accC00 += wt * gvn.x * gxx;
            accC01 += wt * gvn.x * gxy;
            accC10 += wt * gvn.y * gxx;
            accC11 += wt * gvn.y * gxy;
        }
    }

    const float k4 = 4.0f * INV_DX * INV_DX;
    out_x[i]   = make_float2(xi.x + DTc * vi.x, xi.y + DTc * vi.y);
    out_v[i]   = make_float2(accvx, accvy);
    out_C[i]   = make_float4(k4 * (accC00 - accvx * xi.x),
                             k4 * (accC01 - accvx * xi.y),
                             k4 * (accC10 - accvy * xi.x),
                             k4 * (accC11 - accvy * xi.y));
    out_mat[i] = (float)material[i];
    out_Jp[i]  = Jp[i];
}

// ---------------------------------------------------------------------------
extern "C" void kernel_launch(void* const* d_in, const int* in_sizes, int n_in,
                              void* d_out, int out_size, void* d_ws, size_t ws_size,
                              hipStream_t stream)
{
    const float2* x  = (const float2*)d_in[0];
    const float2* v  = (const float2*)d_in[1];
    const float4* C  = (const float4*)d_in[2];
    const float4* F  = (const float4*)d_in[3];
    const int* material = (const int*)d_in[4];
    const float* Jp  = (const float*)d_in[5];
    const float* W1  = (const float*)d_in[8];
    const float* b1  = (const float*)d_in[9];
    const float* W2  = (const float*)d_in[10];
    const float* b2  = (const float*)d_in[11];
    const float* W3  = (const float*)d_in[12];
    const float* b3  = (const float*)d_in[13];
    const float* W4  = (const float*)d_in[14];

    const int n = in_sizes[0] / 2;

    // d_ws: gcnt (NBIN u32) + binoff (NBIN+1 u32) + gv (NCELL float2)
    unsigned* gcnt   = (unsigned*)d_ws;
    unsigned* binoff = gcnt + NBIN;
    float2*   gv     = (float2*)(binoff + NBIN + 1);

    float* out = (float*)d_out;
    float2* out_x   = (float2*)out;                    // 0..2N
    float2* out_v   = (float2*)(out + 2 * (size_t)n);  // 2N..4N
    float4* out_C   = (float4*)(out + 4 * (size_t)n);  // 4N..8N
    float4* out_F   = (float4*)(out + 8 * (size_t)n);  // 8N..12N  (written by stagea)
    float*  out_mat = out + 12 * (size_t)n;            // 12N..13N
    float*  out_Jp  = out + 13 * (size_t)n;            // 13N..14N

    // middle-phase scratch inside d_out (consumed before g2p overwrites):
    // recs occupies out[0..8N) = out_x/out_v/out_C regions, all written only
    // by g2p which runs after grid_gather has consumed recs.
    float4*   recs = (float4*)out;                     // 8N floats: 0..8N
    unsigned* key  = (unsigned*)out_mat;               // N u32:     12N..13N

    hipMemsetAsync(gcnt, 0, NBIN * sizeof(unsigned), stream);

    int s1_blocks = (n + S1_BLK * S1_PPT - 1) / (S1_BLK * S1_PPT);
    int blocks    = (n + 255) / 256;
    int a_blocks  = (n + 256 * A_PPT - 1) / (256 * A_PPT);
    bin_kernel<<<s1_blocks, S1_BLK, 0, stream>>>(x, key, gcnt, n);
    scan_kernel<<<1, 1024, 0, stream>>>(gcnt, binoff);
    stagea_kernel<<<a_blocks, 256, 0, stream>>>(x, v, C, F, W1, b1, W2, b2, W3, b3, W4,
                                                key, binoff, recs, out_F, n);
    grid_gather_kernel<<<NCELL / 4, 256, 0, stream>>>(recs, binoff, gv);
    g2p_kernel<<<blocks, 256, 0, stream>>>(x, v, material, Jp, gv,
                                           out_x, out_v, out_C, out_mat, out_Jp, n);
}